// Round 22
// baseline (237.052 us; speedup 1.0000x reference)
//
#include <hip/hip_runtime.h>
#include <hip/hip_bf16.h>
#include <stdint.h>

#define B_   2
#define S_   2048
#define D_   1024
#define H_   16
#define DH_  64
#define HID_ 4096
#define M_   4096  // B_*S_

typedef __bf16 bf16x8 __attribute__((ext_vector_type(8)));
typedef float  f32x4  __attribute__((ext_vector_type(4)));
typedef float  f32x16 __attribute__((ext_vector_type(16)));
typedef uint32_t u32x4v __attribute__((ext_vector_type(4)));

typedef const uint32_t __attribute__((address_space(1))) u32g;
typedef uint32_t       __attribute__((address_space(3))) u32l;

#define SCL2K_ 0.18033688011112042f  // 0.125 * log2(e), folded into K at QKV epi

__device__ __forceinline__ uint16_t f2bf(float f) {
  uint32_t u = __builtin_bit_cast(uint32_t, f);
  u += 0x7FFFu + ((u >> 16) & 1u);   // RNE
  return (uint16_t)(u >> 16);
}

__device__ __forceinline__ float bf2f(uint16_t u) {
  return __builtin_bit_cast(float, (uint32_t)u << 16);
}

__device__ __forceinline__ void gload_lds16(const void* g, void* l) {
  __builtin_amdgcn_global_load_lds((u32g*)g, (u32l*)l, 16, 0, 0);
}

// swizzled LDS 16B read: row-major [*][64] bf16 tile, byte ^= (row&7)<<4
__device__ __forceinline__ const bf16x8* lds8p(const uint16_t* base, int row,
                                               int cole) {
  int byt = (cole * 2) ^ ((row & 7) << 4);
  return reinterpret_cast<const bf16x8*>(base + row * 64 + (byt >> 1));
}

// 4-bit swizzle variant for the attention 32-row tiles
__device__ __forceinline__ const bf16x8* lds8p32(const uint16_t* base, int row,
                                                 int cole) {
  int byt = (cole * 2) ^ ((row & 7) << 4) ^ ((row & 8) << 2);
  return reinterpret_cast<const bf16x8*>(base + row * 64 + (byt >> 1));
}

__device__ __forceinline__ uint32_t cvtpk_bf16(float lo, float hi) {
  uint32_t d;
  asm("v_cvt_pk_bf16_f32 %0, %1, %2" : "=v"(d) : "v"(lo), "v"(hi));
  return d;
}
__device__ __forceinline__ void pl32swap(uint32_t& a, uint32_t& b) {
  asm volatile("v_permlane32_swap_b32 %0, %1" : "+v"(a), "+v"(b));
}

// ------ prep: ALL weight converts + LN1 in ONE launch (256 thr as (32,8)) -----
__global__ void prep_k(const float* __restrict__ Wq, const float* __restrict__ Wk,
                       const float* __restrict__ Wv, const float* __restrict__ Wo,
                       const float* __restrict__ W1, const float* __restrict__ W2,
                       uint16_t* __restrict__ WQKVT, uint16_t* __restrict__ WOT,
                       uint16_t* __restrict__ W1T, uint16_t* __restrict__ W2T,
                       const float* __restrict__ x, const float* __restrict__ sc,
                       const float* __restrict__ sh, uint16_t* __restrict__ lnout) {
  int idx = blockIdx.x;
  int tx = threadIdx.x, ty = threadIdx.y;
  if (idx >= 12288) {  // LN1 branch
    int row = idx - 12288;
    int t = ty * 32 + tx;
    float4 v = reinterpret_cast<const float4*>(x + (size_t)row * D_)[t];
    float s = v.x + v.y + v.z + v.w;
    float ss = v.x * v.x + v.y * v.y + v.z * v.z + v.w * v.w;
#pragma unroll
    for (int off = 32; off >= 1; off >>= 1) {
      s += __shfl_xor(s, off);
      ss += __shfl_xor(ss, off);
    }
    __shared__ float red[8];
    int wid = t >> 6, lane = t & 63;
    if (lane == 0) { red[wid] = s; red[wid + 4] = ss; }
    __syncthreads();
    s = red[0] + red[1] + red[2] + red[3];
    ss = red[4] + red[5] + red[6] + red[7];
    float mean = s * (1.0f / D_);
    float var = ss * (1.0f / D_) - mean * mean;
    float rstd = rsqrtf(var + 1e-5f);
    float4 g = reinterpret_cast<const float4*>(sc)[t];
    float4 b = reinterpret_cast<const float4*>(sh)[t];
    ushort4 o;
    o.x = f2bf(g.x * (v.x - mean) * rstd + b.x);
    o.y = f2bf(g.y * (v.y - mean) * rstd + b.y);
    o.z = f2bf(g.z * (v.z - mean) * rstd + b.z);
    o.w = f2bf(g.w * (v.w - mean) * rstd + b.w);
    reinterpret_cast<ushort4*>(lnout + (size_t)row * D_)[t] = o;
    return;
  }
  __shared__ float tile[32][33];
  const float* W;
  uint16_t* WT;
  int K, N, within;
  if (idx < 4096) {
    int which = idx >> 10;
    within = idx & 1023;
    W = (which == 0) ? Wq : (which == 1) ? Wk : (which == 2) ? Wv : Wo;
    WT = (which == 3) ? WOT : WQKVT + (size_t)which * 1024 * 1024;
    K = 1024; N = 1024;
  } else if (idx < 8192) {
    within = idx - 4096; W = W1; WT = W1T; K = 1024; N = 4096;
  } else {
    within = idx - 8192; W = W2; WT = W2T; K = 4096; N = 1024;
  }
  int nb = N >> 5;
  int n0 = (within % nb) * 32, k0 = (within / nb) * 32;
#pragma unroll
  for (int i = 0; i < 4; ++i)
    tile[ty + i * 8][tx] = W[(size_t)(k0 + ty + i * 8) * N + n0 + tx];
  __syncthreads();
#pragma unroll
  for (int i = 0; i < 4; ++i)
    WT[(size_t)(n0 + ty + i * 8) * K + k0 + tx] = f2bf(tile[tx][ty + i * 8]);
}

// ------ layernorm (LN2): sums TWO bf16 partial rows (Wo split-K) -> bf16 ------
__global__ __launch_bounds__(256) void ln_k(const uint16_t* __restrict__ xa,
                                            const uint16_t* __restrict__ xb,
                                            const float* __restrict__ sc,
                                            const float* __restrict__ sh,
                                            uint16_t* __restrict__ out) {
  int row = blockIdx.x;
  int t = threadIdx.x;
  ushort4 ua = reinterpret_cast<const ushort4*>(xa + (size_t)row * D_)[t];
  ushort4 ub = reinterpret_cast<const ushort4*>(xb + (size_t)row * D_)[t];
  float vx = bf2f(ua.x) + bf2f(ub.x), vy = bf2f(ua.y) + bf2f(ub.y);
  float vz = bf2f(ua.z) + bf2f(ub.z), vw = bf2f(ua.w) + bf2f(ub.w);
  float s = vx + vy + vz + vw;
  float ss = vx * vx + vy * vy + vz * vz + vw * vw;
#pragma unroll
  for (int off = 32; off >= 1; off >>= 1) {
    s += __shfl_xor(s, off);
    ss += __shfl_xor(ss, off);
  }
  __shared__ float red[8];
  int wid = t >> 6, lane = t & 63;
  if (lane == 0) { red[wid] = s; red[wid + 4] = ss; }
  __syncthreads();
  s = red[0] + red[1] + red[2] + red[3];
  ss = red[4] + red[5] + red[6] + red[7];
  float mean = s * (1.0f / D_);
  float var = ss * (1.0f / D_) - mean * mean;
  float rstd = rsqrtf(var + 1e-5f);
  float4 g = reinterpret_cast<const float4*>(sc)[t];
  float4 b = reinterpret_cast<const float4*>(sh)[t];
  ushort4 o;
  o.x = f2bf(g.x * (vx - mean) * rstd + b.x);
  o.y = f2bf(g.y * (vy - mean) * rstd + b.y);
  o.z = f2bf(g.z * (vz - mean) * rstd + b.z);
  o.w = f2bf(g.w * (vw - mean) * rstd + b.w);
  reinterpret_cast<ushort4*>(out + (size_t)row * D_)[t] = o;
}

// -- out = residA+residB (bf16 Wo partials) + bias + 4 bf16 FFN2 partials ------
__global__ __launch_bounds__(256) void reduce4_k(
    const uint16_t* __restrict__ P0, const uint16_t* __restrict__ P1,
    const uint16_t* __restrict__ P2, const uint16_t* __restrict__ P3,
    const uint16_t* __restrict__ ra, const uint16_t* __restrict__ rb,
    const float* __restrict__ bias, float* __restrict__ out) {
  int row = blockIdx.x, t = threadIdx.x;
  size_t base = (size_t)row * D_ + t * 4;
  ushort4 uA = *reinterpret_cast<const ushort4*>(ra + base);
  ushort4 uB = *reinterpret_cast<const ushort4*>(rb + base);
  float4 b = reinterpret_cast<const float4*>(bias)[t];
  ushort4 u0 = *reinterpret_cast<const ushort4*>(P0 + base);
  ushort4 u1 = *reinterpret_cast<const ushort4*>(P1 + base);
  ushort4 u2 = *reinterpret_cast<const ushort4*>(P2 + base);
  ushort4 u3 = *reinterpret_cast<const ushort4*>(P3 + base);
  float4 o;
  o.x = bf2f(uA.x) + bf2f(uB.x) + b.x + bf2f(u0.x) + bf2f(u1.x) + bf2f(u2.x) + bf2f(u3.x);
  o.y = bf2f(uA.y) + bf2f(uB.y) + b.y + bf2f(u0.y) + bf2f(u1.y) + bf2f(u2.y) + bf2f(u3.y);
  o.z = bf2f(uA.z) + bf2f(uB.z) + b.z + bf2f(u0.z) + bf2f(u1.z) + bf2f(u2.z) + bf2f(u3.z);
  o.w = bf2f(uA.w) + bf2f(uB.w) + b.w + bf2f(u0.w) + bf2f(u1.w) + bf2f(u2.w) + bf2f(u3.w);
  *reinterpret_cast<float4*>(out + base) = o;
}

// ================== 256x256 8-phase GEMM (structure frozen, R20) ==============
template <int EPI>
__global__ __launch_bounds__(512, 2) void gemm8(
    const uint16_t* __restrict__ A, const uint16_t* __restrict__ BT,
    void* __restrict__ Cout, const float* __restrict__ bias,
    uint16_t* __restrict__ P0, uint16_t* __restrict__ P1,
    uint16_t* __restrict__ P2, uint16_t* __restrict__ P3,
    int M, int N, int K) {
  constexpr int KSZ = 1024;
  constexpr int NT = KSZ >> 6;  // 16
  __shared__ uint16_t As[2][2][128 * 64];
  __shared__ uint16_t Bs[2][2][128 * 64];
  int t = threadIdx.x;
  int lane = t & 63, wid = t >> 6;
  int wm = wid >> 2, wn = wid & 3;
  int l15 = lane & 15, lk8 = (lane >> 4) * 8, lr4 = (lane >> 4) * 4;
  int gx = gridDim.x;
  int nwg = gx * gridDim.y;
  int bid = blockIdx.y * gx + blockIdx.x;
  int swz = (bid & 7) * (nwg >> 3) + (bid >> 3);
  int bx = swz % gx, by = swz / gx;
  int m0 = by * 256, n0 = bx * 256;
  int kbeg = blockIdx.z * KSZ;

  int r0 = t >> 3, slot0 = t & 7;
  int scol = (slot0 ^ (r0 & 7)) * 8;  // pre-swizzled source col (involution)

  auto STAGE_A = [&](int kt, int half, int buf) {
    const uint16_t* src =
        A + (size_t)(m0 + half * 128 + r0) * K + kbeg + kt * 64 + scol;
    uint16_t* dst = &As[buf][half][t * 8];
    gload_lds16(src, dst);
    gload_lds16(src + (size_t)64 * K, dst + 4096);
  };
  auto STAGE_B = [&](int kt, int half, int buf) {
    const uint16_t* src =
        BT + (size_t)(n0 + half * 128 + r0) * K + kbeg + kt * 64 + scol;
    uint16_t* dst = &Bs[buf][half][t * 8];
    gload_lds16(src, dst);
    gload_lds16(src + (size_t)64 * K, dst + 4096);
  };

  // double-banked fragments (named banks; static indexing per rule #20)
  bf16x8 aA[4][2], aB[4][2], bA[2][2], bB[2][2];
  auto LDAf = [&](bf16x8 (&dst)[4][2], int buf, int mh) {
#pragma unroll
    for (int j = 0; j < 4; ++j)
#pragma unroll
      for (int kk = 0; kk < 2; ++kk)
        dst[j][kk] = *lds8p(As[buf][mh], wm * 64 + j * 16 + l15, kk * 32 + lk8);
  };
  auto LDBf = [&](bf16x8 (&dst)[2][2], int buf, int nh) {
#pragma unroll
    for (int jj = 0; jj < 2; ++jj)
#pragma unroll
      for (int kk = 0; kk < 2; ++kk)
        dst[jj][kk] = *lds8p(Bs[buf][nh], wn * 32 + jj * 16 + l15, kk * 32 + lk8);
  };

  f32x4 acc[8][4] = {};
  auto MMf = [&](bf16x8 (&a)[4][2], bf16x8 (&b)[2][2], int mh, int nh) {
    __builtin_amdgcn_s_setprio(1);
#pragma unroll
    for (int kk = 0; kk < 2; ++kk)
#pragma unroll
      for (int j = 0; j < 4; ++j)
#pragma unroll
        for (int jj = 0; jj < 2; ++jj)
          acc[mh * 4 + j][nh * 2 + jj] = __builtin_amdgcn_mfma_f32_16x16x32_bf16(
              a[j][kk], b[jj][kk], acc[mh * 4 + j][nh * 2 + jj], 0, 0, 0);
    __builtin_amdgcn_s_setprio(0);
  };
  auto BAR = [&]() { __builtin_amdgcn_s_barrier(); };  // bare: NO memory clobber

  STAGE_A(0, 0, 0);
  STAGE_B(0, 1, 0);
  STAGE_B(0, 0, 0);
  STAGE_A(0, 1, 0);
  STAGE_A(1, 0, 1);
  STAGE_B(1, 1, 1);
  asm volatile("s_waitcnt vmcnt(4)" ::: "memory");
  BAR();
  // prologue fragments: A0, B0 of tile 0 (buf 0)
  LDAf(aA, 0, 0);
  LDBf(bA, 0, 0);

#pragma unroll
  for (int T = 0; T < NT; ++T) {
    int cur = T & 1;  // folds under full unroll
    if (T + 1 < NT) STAGE_B(T + 1, 0, cur ^ 1);
    BAR();
    LDBf(bB, cur, 1);
    MMf(aA, bA, 0, 0);
    BAR();
    if (T + 1 < NT) STAGE_A(T + 1, 1, cur ^ 1);
    BAR();
    LDAf(aB, cur, 1);
    MMf(aA, bB, 0, 1);
    BAR();
    if (T + 2 < NT) STAGE_A(T + 2, 0, cur);
    BAR();
    MMf(aB, bB, 1, 1);
    BAR();
    if (T + 2 < NT) STAGE_B(T + 2, 1, cur);
    BAR();
    MMf(aB, bA, 1, 0);
    if (T + 1 < NT) {
      if (T == NT - 2) {
        asm volatile("s_waitcnt vmcnt(0)" ::: "memory");
      } else {
        asm volatile("s_waitcnt vmcnt(4)" ::: "memory");
      }
    }
    BAR();
    if (T + 1 < NT) {
      LDAf(aA, cur ^ 1, 0);
      LDBf(bA, cur ^ 1, 0);
    }
  }

  uint16_t* Pz = nullptr;
  if constexpr (EPI == 3) {
    int z = blockIdx.z;
    Pz = (z == 0) ? P0 : (z == 1) ? P1 : (z == 2) ? P2 : P3;
  }
#pragma unroll
  for (int mi = 0; mi < 8; ++mi) {
#pragma unroll
    for (int ni = 0; ni < 4; ++ni) {
      int gm0 = m0 + (mi >> 2) * 128 + wm * 64 + (mi & 3) * 16 + lr4;
      int gn = n0 + (ni >> 1) * 128 + wn * 32 + (ni & 1) * 16 + l15;
      if constexpr (EPI == 0) {
        int which = gn >> 10, nc = gn & 1023;
        int h = nc >> 6, dh = nc & 63;
        int bb = gm0 >> 11, s0 = gm0 & 2047;
        if (which == 2) {
          // V: write directly transposed into VTb (bh,dh,s); 4 consecutive s
          ushort4 vs;
          vs.x = f2bf(acc[mi][ni][0]);
          vs.y = f2bf(acc[mi][ni][1]);
          vs.z = f2bf(acc[mi][ni][2]);
          vs.w = f2bf(acc[mi][ni][3]);
          uint16_t* VTb = P0;  // passed via P0 slot
          *reinterpret_cast<ushort4*>(
              VTb + ((size_t)(bb * 16 + h) * 64 + dh) * S_ + s0) = vs;
        } else {
#pragma unroll
          for (int rr = 0; rr < 4; ++rr) {
            float v = acc[mi][ni][rr];
            if (which == 1) v *= SCL2K_;  // fold softmax scale into K
            ((uint16_t*)Cout)[((size_t)which * 32 + bb * 16 + h) * (S_ * 64) +
                              (size_t)(s0 + rr) * 64 + dh] = f2bf(v);
          }
        }
      } else {
#pragma unroll
        for (int rr = 0; rr < 4; ++rr) {
          int gm = gm0 + rr;
          float v = acc[mi][ni][rr];
          if constexpr (EPI == 2) {
            float u = v + bias[gn];
            float y = 0.7978845608028654f * (u + 0.044715f * u * u * u);
            float e = __expf(2.0f * y);
            float th = 1.0f - 2.0f / (e + 1.0f);  // tanh(y), inf-safe
            ((uint16_t*)Cout)[(size_t)gm * N + gn] = f2bf(0.5f * u * (1.0f + th));
          } else {
            Pz[(size_t)gm * N + gn] = f2bf(v);
          }
        }
      }
    }
  }
}

// --- 128x128 2-phase GEMM (Wo only), R22: split-K via gridDim.z (2 blocks/CU).
// z=0 writes bf16 partial = x + acc(K lo half) + bo; z=1 writes bf16 acc(K hi).
// Consumers (ln_k, reduce4_k) sum the two partials. No atomics (R6 lesson).
template <int EPI>
__global__ __launch_bounds__(256) void gemm_bt(
    const uint16_t* __restrict__ A, const uint16_t* __restrict__ BT,
    void* __restrict__ Cout, const float* __restrict__ bias,
    const float* __restrict__ resid, int M, int N, int K) {
  __shared__ uint16_t Asm_[128 * 64];
  __shared__ uint16_t Bsm_[128 * 64];
  int t = threadIdx.x;
  int lane = t & 63, wid = t >> 6;
  int wr = wid >> 1, wc = wid & 1;
  int nwg = gridDim.x * gridDim.y;
  int bid = blockIdx.y * gridDim.x + blockIdx.x;
  int swz = (bid & 7) * (nwg >> 3) + (bid >> 3);
  int bx = swz % gridDim.x, by = swz / gridDim.x;
  int m0 = by * 128, n0 = bx * 128;
  int l15 = lane & 15, lk8 = (lane >> 4) * 8;
  int ksz = K / gridDim.z;
  int kbeg = blockIdx.z * ksz;
  f32x4 acc[4][4] = {};

  auto STAGE = [&](int k0) {
#pragma unroll
    for (int it = 0; it < 4; ++it) {
      int idx = it * 256 + t;
      int r = idx >> 3, slot = idx & 7;
      int c = (slot ^ (r & 7)) * 8;
      gload_lds16(A + (size_t)(m0 + r) * K + k0 + c, &Asm_[idx * 8]);
      gload_lds16(BT + (size_t)(n0 + r) * K + k0 + c, &Bsm_[idx * 8]);
    }
  };

  int niter = ksz >> 6;
  for (int ki = 0; ki < niter; ++ki) {
    __syncthreads();
    STAGE(kbeg + ki * 64);
    __syncthreads();
#pragma unroll
    for (int kk = 0; kk < 2; ++kk) {
      bf16x8 a[4], b[4];
#pragma unroll
      for (int mi = 0; mi < 4; ++mi)
        a[mi] = *lds8p(Asm_, wr * 64 + mi * 16 + l15, kk * 32 + lk8);
#pragma unroll
      for (int ni = 0; ni < 4; ++ni)
        b[ni] = *lds8p(Bsm_, wc * 64 + ni * 16 + l15, kk * 32 + lk8);
#pragma unroll
      for (int mi = 0; mi < 4; ++mi)
#pragma unroll
        for (int ni = 0; ni < 4; ++ni)
          acc[mi][ni] = __builtin_amdgcn_mfma_f32_16x16x32_bf16(
              a[mi], b[ni], acc[mi][ni], 0, 0, 0);
    }
  }
  int lr4 = (lane >> 4) * 4;
  uint16_t* outp = (uint16_t*)Cout + (size_t)blockIdx.z * M * N;
#pragma unroll
  for (int mi = 0; mi < 4; ++mi) {
#pragma unroll
    for (int ni = 0; ni < 4; ++ni) {
#pragma unroll
      for (int r = 0; r < 4; ++r) {
        int gm = m0 + wr * 64 + mi * 16 + lr4 + r;
        int gn = n0 + wc * 64 + ni * 16 + l15;
        float v = acc[mi][ni][r];
        if constexpr (EPI == 1) {
          if (blockIdx.z == 0)
            outp[(size_t)gm * N + gn] =
                f2bf(resid[(size_t)gm * N + gn] + v + bias[gn]);
          else
            outp[(size_t)gm * N + gn] = f2bf(v);
        }
      }
    }
  }
}

// ===== flash causal attention: split-S=3 + LPT ordering + LDS-staged 32x32 ====
__global__ __launch_bounds__(64) void attn32s_k(const uint16_t* __restrict__ Q,
                                                const uint16_t* __restrict__ Kv,
                                                const uint16_t* __restrict__ VT,
                                                uint16_t* __restrict__ Obuf,
                                                float* __restrict__ ML) {
  __shared__ uint16_t Ksm[2][32 * 64];
  __shared__ uint16_t Vsm[2][32 * 64];
  int bid = blockIdx.x;
  int bh = bid & 31;            // bid%8 == bh%8: head's K/V stays on one XCD L2
  int s = (bid >> 5) % 3;
  int qt = 63 - bid / 96;       // LPT: heaviest first
  int lane = threadIdx.x;
  int l31 = lane & 31, lh = lane >> 5;
  int nkt = qt + 1;
  int chunk = (nkt + 2) / 3;
  int t0 = s * chunk, t1 = min(nkt, t0 + chunk);
  int pb = (qt * 32 + bh) * 3 + s;

  f32x16 o0 = {}, o1 = {};
  float mrow = -3.0e38f, lsum = 0.0f;

  auto STAGE = [&](int k0, int bufi) {
#pragma unroll
    for (int c = 0; c < 4; ++c) {
      int idx = c * 64 + lane;
      int r = idx >> 3, sl = idx & 7;
      int slp = sl ^ (r & 7) ^ ((r & 8) >> 2);  // pre-swizzled source slot
      gload_lds16(Kv + ((size_t)bh * S_ + k0 + r) * 64 + slp * 8,
                  &Ksm[bufi][idx * 8]);
      int dh = 2 * r + (slp >> 2), ko = (slp & 3) * 8;
      gload_lds16(VT + ((size_t)bh * 64 + dh) * S_ + k0 + ko,
                  &Vsm[bufi][idx * 8]);
    }
  };

  if (t0 < t1) {
    int qbase = qt * 32;
    bf16x8 qf[4];
#pragma unroll
    for (int dk = 0; dk < 4; ++dk)
      qf[dk] = *reinterpret_cast<const bf16x8*>(
          Q + ((size_t)bh * S_ + qbase + l31) * 64 + dk * 16 + lh * 8);

    int buf = 0;
    STAGE(t0 * 32, 0);
    for (int t = t0; t < t1; ++t) {
      if (t + 1 < t1) {
        STAGE((t + 1) * 32, buf ^ 1);
        asm volatile("s_waitcnt vmcnt(8)" ::: "memory");
      } else {
        asm volatile("s_waitcnt vmcnt(0)" ::: "memory");
      }
      __builtin_amdgcn_sched_barrier(0);
      // QK^T swapped: Sf[key reg][q col], keys t*32..t*32+31
      f32x16 Sf = {};
      __builtin_amdgcn_s_setprio(1);
#pragma unroll
      for (int dk = 0; dk < 4; ++dk) {
        bf16x8 kf = *lds8p32(Ksm[buf], l31, dk * 16 + lh * 8);
        Sf = __builtin_amdgcn_mfma_f32_32x32x16_bf16(kf, qf[dk], Sf, 0, 0, 0);
      }
      __builtin_amdgcn_s_setprio(0);
      float sv[16];
      if (t == qt) {  // diagonal tile: key(reg) <= q(lane)
#pragma unroll
        for (int rr = 0; rr < 16; ++rr) {
          int koff = (rr & 3) + 8 * (rr >> 2) + 4 * lh;
          sv[rr] = (koff <= l31) ? Sf[rr] : -3.0e38f;
        }
      } else {
#pragma unroll
        for (int rr = 0; rr < 16; ++rr) sv[rr] = Sf[rr];
      }
      // per-lane max tree; wave reduce + rescale only on growth > 8 (exp2 dom)
      float mt16 = sv[0];
#pragma unroll
      for (int rr = 1; rr < 16; ++rr) mt16 = fmaxf(mt16, sv[rr]);
      if (__any(mt16 > mrow + 8.0f)) {
        float mt = mt16;
#pragma unroll
        for (int off = 32; off >= 1; off >>= 1)
          mt = fmaxf(mt, __shfl_xor(mt, off));
        mt = fmaxf(mt, mrow);
        float fac = __builtin_amdgcn_exp2f(mrow - mt);
        mrow = mt;
        lsum *= fac;
#pragma unroll
        for (int rr = 0; rr < 16; ++rr) { o0[rr] *= fac; o1[rr] *= fac; }
      }
      float pv[16];
#pragma unroll
      for (int rr = 0; rr < 16; ++rr) {
        pv[rr] = __builtin_amdgcn_exp2f(sv[rr] - mrow);
        lsum += pv[rr];
      }
      // P -> two bf16 A-frags (keys 0-15, 16-31) via cvt_pk + permlane32_swap
      uint32_t a0 = cvtpk_bf16(pv[0], pv[1]), b0 = cvtpk_bf16(pv[4], pv[5]);
      pl32swap(a0, b0);
      uint32_t a1 = cvtpk_bf16(pv[2], pv[3]), b1 = cvtpk_bf16(pv[6], pv[7]);
      pl32swap(a1, b1);
      u32x4v w0 = {a0, a1, b0, b1};
      bf16x8 pa0 = __builtin_bit_cast(bf16x8, w0);
      uint32_t a2 = cvtpk_bf16(pv[8], pv[9]), b2 = cvtpk_bf16(pv[12], pv[13]);
      pl32swap(a2, b2);
      uint32_t a3 = cvtpk_bf16(pv[10], pv[11]), b3 = cvtpk_bf16(pv[14], pv[15]);
      pl32swap(a3, b3);
      u32x4v w1 = {a2, a3, b2, b3};
      bf16x8 pa1 = __builtin_bit_cast(bf16x8, w1);
      // PV: o[q][dh] += P[q][key] * V[key][dh]
      int vrow = l31 >> 1, vcb = (l31 & 1) * 32 + lh * 8;
      __builtin_amdgcn_s_setprio(1);
      bf16x8 v00 = *lds8p32(Vsm[buf], vrow, vcb);
      o0 = __builtin_amdgcn_mfma_f32_32x32x16_bf16(pa0, v00, o0, 0, 0, 0);
      bf16x8 v01 = *lds8p32(Vsm[buf], vrow, vcb + 16);
      o0 = __builtin_amdgcn_mfma_f32_32x32x16_bf16(pa1, v01, o0, 0, 0, 0);
      bf16x8 v10 = *lds8p32(Vsm[buf], 16 + vrow, vcb);
      o1 = __builtin_amdgcn_mfma_f32_32x32x16_bf16(pa0, v10, o1, 0, 0, 0);
      bf16x8 v11 = *lds8p32(Vsm[buf], 16 + vrow, vcb + 16);
      o1 = __builtin_amdgcn_mfma_f32_32x32x16_bf16(pa1, v11, o1, 0, 0, 0);
      __builtin_amdgcn_s_setprio(0);
      buf ^= 1;
    }
    lsum += __shfl_xor(lsum, 32);  // combine lh halves -> full row sum for q=l31
  }

  // write partial: unnormalized o (bf16) + per-q (m, l) f32
  if (lane < 32) {
    ML[(size_t)pb * 64 + l31 * 2] = mrow;
    ML[(size_t)pb * 64 + l31 * 2 + 1] = lsum;
  }
#pragma unroll
  for (int rr = 0; rr < 16; ++rr) {
    int srow = (rr & 3) + 8 * (rr >> 2) + 4 * lh;
    size_t base = (size_t)pb * 2048 + srow * 64;
    Obuf[base + l31] = f2bf(o0[rr]);
    Obuf[base + 32 + l31] = f2bf(o1[rr]);
  }
}

// combine (3-way): ctx = sum_s o_s*2^(m_s-m) / sum_s l_s*2^(m_s-m)
__global__ __launch_bounds__(64) void attncomb_k(const uint16_t* __restrict__ Obuf,
                                                 const float* __restrict__ ML,
                                                 uint16_t* __restrict__ ctx) {
  int blk = blockIdx.x;  // qt*32 + bh
  int qt = blk >> 5, bh = blk & 31;
  int lane = threadIdx.x;
  int q = lane >> 1, half = lane & 1;
  size_t pb0 = (size_t)blk * 3;
  float m0 = ML[pb0 * 64 + q * 2], l0 = ML[pb0 * 64 + q * 2 + 1];
  float m1 = ML[(pb0 + 1) * 64 + q * 2], l1 = ML[(pb0 + 1) * 64 + q * 2 + 1];
  float m2 = ML[(pb0 + 2) * 64 + q * 2], l2 = ML[(pb0 + 2) * 64 + q * 2 + 1];
  float m = fmaxf(fmaxf(m0, m1), m2);
  float w0 = __builtin_amdgcn_exp2f(m0 - m);
  float w1 = __builtin_amdgcn_exp2f(m1 - m);
  float w2 = __builtin_amdgcn_exp2f(m2 - m);
  float invL = 1.0f / (l0 * w0 + l1 * w1 + l2 * w2);
  int b_ = bh >> 4, h_ = bh & 15;
  int srow = qt * 32 + q;
  size_t ib = pb0 * 2048 + q * 64 + half * 32;
  size_t ob = ((size_t)(b_ * S_ + srow)) * D_ + h_ * 64 + half * 32;
#pragma unroll
  for (int i = 0; i < 8; ++i) {
    ushort4 u0 = *reinterpret_cast<const ushort4*>(Obuf + ib + i * 4);
    ushort4 u1 = *reinterpret_cast<const ushort4*>(Obuf + 2048 + ib + i * 4);
    ushort4 u2 = *reinterpret_cast<const ushort4*>(Obuf + 4096 + ib + i * 4);
    ushort4 o;
    o.x = f2bf((bf2f(u0.x) * w0 + bf2f(u1.x) * w1 + bf2f(u2.x) * w2) * invL);
    o.y = f2bf((bf2f(u0.y) * w0 + bf2f(u1.y) * w1 + bf2f(u2.y) * w2) * invL);
    o.z = f2bf((bf2f(u0.z) * w0 + bf2f(u1.z) * w1 + bf2f(u2.z) * w2) * invL);
    o.w = f2bf((bf2f(u0.w) * w0 + bf2f(u1.w) * w1 + bf2f(u2.w) * w2) * invL);
    *reinterpret_cast<ushort4*>(ctx + ob + i * 4) = o;
  }
}

extern "C" void kernel_launch(void* const* d_in, const int* in_sizes, int n_in,
                              void* d_out, int out_size, void* d_ws, size_t ws_size,
                              hipStream_t stream) {
  const float* x    = (const float*)d_in[0];
  const float* Wq   = (const float*)d_in[1];
  const float* Wk   = (const float*)d_in[2];
  const float* Wv   = (const float*)d_in[3];
  const float* Wo   = (const float*)d_in[4];
  const float* bo   = (const float*)d_in[5];
  const float* W1   = (const float*)d_in[6];
  const float* b1   = (const float*)d_in[7];
  const float* W2   = (const float*)d_in[8];
  const float* b2   = (const float*)d_in[9];
  const float* ln1s = (const float*)d_in[10];
  const float* ln1b = (const float*)d_in[11];
  const float* ln2s = (const float*)d_in[12];
  const float* ln2b = (const float*)d_in[13];
  float* out = (float*)d_out;
  char* ws = (char*)d_ws;

  const size_t MB = 1024 * 1024;
  uint16_t* WQKVT = (uint16_t*)(ws + 0);        // 6 MB (dead after QKV gemm)
  uint16_t* WOT   = (uint16_t*)(ws + 6 * MB);   // 2 MB (live until Wo)
  uint16_t* W1T   = (uint16_t*)(ws + 8 * MB);   // 8 MB (live until FFN1)
  uint16_t* W2T   = (uint16_t*)(ws + 16 * MB);  // 8 MB (live until FFN2)
  uint16_t* H1    = (uint16_t*)(ws + 24 * MB);  // 8 MB (LN1/LN2 out)
  uint16_t* X1    = (uint16_t*)(ws + 32 * MB);  // 16 MB: two bf16 Wo partials
  uint16_t* X1b   = (uint16_t*)(ws + 40 * MB);  //   (z=0 at 32, z=1 at 40)
  uint16_t* QKV   = (uint16_t*)(ws + 48 * MB);  // 24 MB (q,k at 48-64)
  uint16_t* VTb   = (uint16_t*)(ws + 72 * MB);  // 8 MB  (v transposed, direct)
  uint16_t* CTX   = (uint16_t*)(ws + 80 * MB);  // 8 MB
  uint16_t* FFH   = (uint16_t*)(ws + 48 * MB);  // 32 MB (reuses dead QKV/VT)
  // attn split-S=3 partials (live attn->combine; X1 written after combine):
  uint16_t* AOB   = (uint16_t*)(ws + 24 * MB);  // 24 MB (6144 pb x 4KB)
  float*    AML   = (float*)(ws + 0);           // 1.5 MB (WQKVT dead by attn)
  // FFN2 split-K bf16 partials (dead regions at FFN2 time):
  uint16_t* SP0   = (uint16_t*)(ws + 0);        // over WQKVT (dead)
  uint16_t* SP1   = (uint16_t*)(ws + 8 * MB);   // over W1T (dead after FFN1)
  uint16_t* SP2   = (uint16_t*)(ws + 24 * MB);  // over H1/AOB (dead after FFN1)
  uint16_t* SP3   = (uint16_t*)(ws + 80 * MB);  // over CTX (dead after Wo)

  dim3 b32x8(32, 8);
  // weight converts + LN1 in one launch
  prep_k<<<dim3(16384), b32x8, 0, stream>>>(Wq, Wk, Wv, Wo, W1, W2,
                                            WQKVT, WOT, W1T, W2T,
                                            x, ln1s, ln1b, H1);
  // QKV projections (fused N=3072), 256^2 8-phase; K pre-scaled; V written
  // directly transposed into VTb (VTb passed via the P0 slot) — no vtrans.
  gemm8<0><<<dim3(12, 16), 512, 0, stream>>>(H1, WQKVT, QKV, nullptr,
                                             VTb, nullptr, nullptr, nullptr,
                                             M_, 3072, 1024);
  const uint16_t* Qp = QKV;
  const uint16_t* Kp = QKV + (size_t)32 * S_ * 64;
  // flash causal attention: split-S=3 LPT, 6144 one-wave blocks + combine
  attn32s_k<<<dim3(6144), 64, 0, stream>>>(Qp, Kp, VTb, AOB, AML);
  attncomb_k<<<dim3(2048), 64, 0, stream>>>(AOB, AML, CTX);
  // Wo projection, split-K=2 (2 blocks/CU): bf16 partials X1 (z0: +x+bo), X1b
  gemm_bt<1><<<dim3(8, 32, 2), 256, 0, stream>>>(CTX, WOT, X1, bo, x,
                                                 M_, 1024, 1024);
  // LN2 -> h2 (bf16, reuse H1); sums the two bf16 Wo partials
  ln_k<<<M_, 256, 0, stream>>>(X1, X1b, ln2s, ln2b, H1);
  // FFN1 + GELU -> FFH (bf16), 256^2 8-phase
  gemm8<2><<<dim3(16, 16), 512, 0, stream>>>(H1, W1T, FFH, b1,
                                             nullptr, nullptr, nullptr, nullptr,
                                             M_, 4096, 1024);
  // FFN2 split-K=4 (ksz=1024), 256^2 8-phase: bf16 partials (plain stores)
  gemm8<3><<<dim3(4, 16, 4), 512, 0, stream>>>(FFH, W2T, nullptr, nullptr,
                                               SP0, SP1, SP2, SP3,
                                               M_, 1024, 4096);
  // out = (X1 + X1b) + b2 + sum(FFN2 partials)
  reduce4_k<<<M_, 256, 0, stream>>>(SP0, SP1, SP2, SP3, X1, X1b, b2, out);
}

// Round 23
// 228.205 us; speedup vs baseline: 1.0388x; 1.0388x over previous
//
#include <hip/hip_runtime.h>
#include <hip/hip_bf16.h>
#include <stdint.h>

#define B_   2
#define S_   2048
#define D_   1024
#define H_   16
#define DH_  64
#define HID_ 4096
#define M_   4096  // B_*S_

typedef __bf16 bf16x8 __attribute__((ext_vector_type(8)));
typedef float  f32x4  __attribute__((ext_vector_type(4)));
typedef float  f32x16 __attribute__((ext_vector_type(16)));
typedef uint32_t u32x4v __attribute__((ext_vector_type(4)));

typedef const uint32_t __attribute__((address_space(1))) u32g;
typedef uint32_t       __attribute__((address_space(3))) u32l;

#define SCL2K_ 0.18033688011112042f  // 0.125 * log2(e), folded into K at QKV epi

__device__ __forceinline__ uint16_t f2bf(float f) {
  uint32_t u = __builtin_bit_cast(uint32_t, f);
  u += 0x7FFFu + ((u >> 16) & 1u);   // RNE
  return (uint16_t)(u >> 16);
}

__device__ __forceinline__ float bf2f(uint16_t u) {
  return __builtin_bit_cast(float, (uint32_t)u << 16);
}

__device__ __forceinline__ void gload_lds16(const void* g, void* l) {
  __builtin_amdgcn_global_load_lds((u32g*)g, (u32l*)l, 16, 0, 0);
}

// swizzled LDS 16B read: row-major [*][64] bf16 tile, byte ^= (row&7)<<4
__device__ __forceinline__ const bf16x8* lds8p(const uint16_t* base, int row,
                                               int cole) {
  int byt = (cole * 2) ^ ((row & 7) << 4);
  return reinterpret_cast<const bf16x8*>(base + row * 64 + (byt >> 1));
}

// 4-bit swizzle variant for the attention 32-row tiles
__device__ __forceinline__ const bf16x8* lds8p32(const uint16_t* base, int row,
                                                 int cole) {
  int byt = (cole * 2) ^ ((row & 7) << 4) ^ ((row & 8) << 2);
  return reinterpret_cast<const bf16x8*>(base + row * 64 + (byt >> 1));
}

__device__ __forceinline__ uint32_t cvtpk_bf16(float lo, float hi) {
  uint32_t d;
  asm("v_cvt_pk_bf16_f32 %0, %1, %2" : "=v"(d) : "v"(lo), "v"(hi));
  return d;
}
__device__ __forceinline__ void pl32swap(uint32_t& a, uint32_t& b) {
  asm volatile("v_permlane32_swap_b32 %0, %1" : "+v"(a), "+v"(b));
}

// ------ prep: ALL weight converts + LN1 in ONE launch (256 thr as (32,8)) -----
__global__ void prep_k(const float* __restrict__ Wq, const float* __restrict__ Wk,
                       const float* __restrict__ Wv, const float* __restrict__ Wo,
                       const float* __restrict__ W1, const float* __restrict__ W2,
                       uint16_t* __restrict__ WQKVT, uint16_t* __restrict__ WOT,
                       uint16_t* __restrict__ W1T, uint16_t* __restrict__ W2T,
                       const float* __restrict__ x, const float* __restrict__ sc,
                       const float* __restrict__ sh, uint16_t* __restrict__ lnout) {
  int idx = blockIdx.x;
  int tx = threadIdx.x, ty = threadIdx.y;
  if (idx >= 12288) {  // LN1 branch
    int row = idx - 12288;
    int t = ty * 32 + tx;
    float4 v = reinterpret_cast<const float4*>(x + (size_t)row * D_)[t];
    float s = v.x + v.y + v.z + v.w;
    float ss = v.x * v.x + v.y * v.y + v.z * v.z + v.w * v.w;
#pragma unroll
    for (int off = 32; off >= 1; off >>= 1) {
      s += __shfl_xor(s, off);
      ss += __shfl_xor(ss, off);
    }
    __shared__ float red[8];
    int wid = t >> 6, lane = t & 63;
    if (lane == 0) { red[wid] = s; red[wid + 4] = ss; }
    __syncthreads();
    s = red[0] + red[1] + red[2] + red[3];
    ss = red[4] + red[5] + red[6] + red[7];
    float mean = s * (1.0f / D_);
    float var = ss * (1.0f / D_) - mean * mean;
    float rstd = rsqrtf(var + 1e-5f);
    float4 g = reinterpret_cast<const float4*>(sc)[t];
    float4 b = reinterpret_cast<const float4*>(sh)[t];
    ushort4 o;
    o.x = f2bf(g.x * (v.x - mean) * rstd + b.x);
    o.y = f2bf(g.y * (v.y - mean) * rstd + b.y);
    o.z = f2bf(g.z * (v.z - mean) * rstd + b.z);
    o.w = f2bf(g.w * (v.w - mean) * rstd + b.w);
    reinterpret_cast<ushort4*>(lnout + (size_t)row * D_)[t] = o;
    return;
  }
  __shared__ float tile[32][33];
  const float* W;
  uint16_t* WT;
  int K, N, within;
  if (idx < 4096) {
    int which = idx >> 10;
    within = idx & 1023;
    W = (which == 0) ? Wq : (which == 1) ? Wk : (which == 2) ? Wv : Wo;
    WT = (which == 3) ? WOT : WQKVT + (size_t)which * 1024 * 1024;
    K = 1024; N = 1024;
  } else if (idx < 8192) {
    within = idx - 4096; W = W1; WT = W1T; K = 1024; N = 4096;
  } else {
    within = idx - 8192; W = W2; WT = W2T; K = 4096; N = 1024;
  }
  int nb = N >> 5;
  int n0 = (within % nb) * 32, k0 = (within / nb) * 32;
#pragma unroll
  for (int i = 0; i < 4; ++i)
    tile[ty + i * 8][tx] = W[(size_t)(k0 + ty + i * 8) * N + n0 + tx];
  __syncthreads();
#pragma unroll
  for (int i = 0; i < 4; ++i)
    WT[(size_t)(n0 + ty + i * 8) * K + k0 + tx] = f2bf(tile[tx][ty + i * 8]);
}

// ---------- layernorm (LN2): bf16 row (1024) -> bf16 ----------
__global__ __launch_bounds__(256) void ln_k(const uint16_t* __restrict__ x,
                                            const float* __restrict__ sc,
                                            const float* __restrict__ sh,
                                            uint16_t* __restrict__ out) {
  int row = blockIdx.x;
  int t = threadIdx.x;
  ushort4 u = reinterpret_cast<const ushort4*>(x + (size_t)row * D_)[t];
  float vx = bf2f(u.x), vy = bf2f(u.y), vz = bf2f(u.z), vw = bf2f(u.w);
  float s = vx + vy + vz + vw;
  float ss = vx * vx + vy * vy + vz * vz + vw * vw;
#pragma unroll
  for (int off = 32; off >= 1; off >>= 1) {
    s += __shfl_xor(s, off);
    ss += __shfl_xor(ss, off);
  }
  __shared__ float red[8];
  int wid = t >> 6, lane = t & 63;
  if (lane == 0) { red[wid] = s; red[wid + 4] = ss; }
  __syncthreads();
  s = red[0] + red[1] + red[2] + red[3];
  ss = red[4] + red[5] + red[6] + red[7];
  float mean = s * (1.0f / D_);
  float var = ss * (1.0f / D_) - mean * mean;
  float rstd = rsqrtf(var + 1e-5f);
  float4 g = reinterpret_cast<const float4*>(sc)[t];
  float4 b = reinterpret_cast<const float4*>(sh)[t];
  ushort4 o;
  o.x = f2bf(g.x * (vx - mean) * rstd + b.x);
  o.y = f2bf(g.y * (vy - mean) * rstd + b.y);
  o.z = f2bf(g.z * (vz - mean) * rstd + b.z);
  o.w = f2bf(g.w * (vw - mean) * rstd + b.w);
  reinterpret_cast<ushort4*>(out + (size_t)row * D_)[t] = o;
}

// ------ out = resid(bf16) + bias + sum of 4 bf16 partials (split-K reduce) ----
__global__ __launch_bounds__(256) void reduce4_k(
    const uint16_t* __restrict__ P0, const uint16_t* __restrict__ P1,
    const uint16_t* __restrict__ P2, const uint16_t* __restrict__ P3,
    const uint16_t* __restrict__ resid, const float* __restrict__ bias,
    float* __restrict__ out) {
  int row = blockIdx.x, t = threadIdx.x;
  size_t base = (size_t)row * D_ + t * 4;
  ushort4 ur = *reinterpret_cast<const ushort4*>(resid + base);
  float4 b = reinterpret_cast<const float4*>(bias)[t];
  ushort4 u0 = *reinterpret_cast<const ushort4*>(P0 + base);
  ushort4 u1 = *reinterpret_cast<const ushort4*>(P1 + base);
  ushort4 u2 = *reinterpret_cast<const ushort4*>(P2 + base);
  ushort4 u3 = *reinterpret_cast<const ushort4*>(P3 + base);
  float4 o;
  o.x = bf2f(ur.x) + b.x + bf2f(u0.x) + bf2f(u1.x) + bf2f(u2.x) + bf2f(u3.x);
  o.y = bf2f(ur.y) + b.y + bf2f(u0.y) + bf2f(u1.y) + bf2f(u2.y) + bf2f(u3.y);
  o.z = bf2f(ur.z) + b.z + bf2f(u0.z) + bf2f(u1.z) + bf2f(u2.z) + bf2f(u3.z);
  o.w = bf2f(ur.w) + b.w + bf2f(u0.w) + bf2f(u1.w) + bf2f(u2.w) + bf2f(u3.w);
  *reinterpret_cast<float4*>(out + base) = o;
}

// ================== 256x256 8-phase GEMM (structure frozen, R20) ==============
template <int EPI>
__global__ __launch_bounds__(512, 2) void gemm8(
    const uint16_t* __restrict__ A, const uint16_t* __restrict__ BT,
    void* __restrict__ Cout, const float* __restrict__ bias,
    uint16_t* __restrict__ P0, uint16_t* __restrict__ P1,
    uint16_t* __restrict__ P2, uint16_t* __restrict__ P3,
    int M, int N, int K) {
  constexpr int KSZ = 1024;
  constexpr int NT = KSZ >> 6;  // 16
  __shared__ uint16_t As[2][2][128 * 64];
  __shared__ uint16_t Bs[2][2][128 * 64];
  int t = threadIdx.x;
  int lane = t & 63, wid = t >> 6;
  int wm = wid >> 2, wn = wid & 3;
  int l15 = lane & 15, lk8 = (lane >> 4) * 8, lr4 = (lane >> 4) * 4;
  int gx = gridDim.x;
  int nwg = gx * gridDim.y;
  int bid = blockIdx.y * gx + blockIdx.x;
  int swz = (bid & 7) * (nwg >> 3) + (bid >> 3);
  int bx = swz % gx, by = swz / gx;
  int m0 = by * 256, n0 = bx * 256;
  int kbeg = blockIdx.z * KSZ;

  int r0 = t >> 3, slot0 = t & 7;
  int scol = (slot0 ^ (r0 & 7)) * 8;  // pre-swizzled source col (involution)

  auto STAGE_A = [&](int kt, int half, int buf) {
    const uint16_t* src =
        A + (size_t)(m0 + half * 128 + r0) * K + kbeg + kt * 64 + scol;
    uint16_t* dst = &As[buf][half][t * 8];
    gload_lds16(src, dst);
    gload_lds16(src + (size_t)64 * K, dst + 4096);
  };
  auto STAGE_B = [&](int kt, int half, int buf) {
    const uint16_t* src =
        BT + (size_t)(n0 + half * 128 + r0) * K + kbeg + kt * 64 + scol;
    uint16_t* dst = &Bs[buf][half][t * 8];
    gload_lds16(src, dst);
    gload_lds16(src + (size_t)64 * K, dst + 4096);
  };

  // double-banked fragments (named banks; static indexing per rule #20)
  bf16x8 aA[4][2], aB[4][2], bA[2][2], bB[2][2];
  auto LDAf = [&](bf16x8 (&dst)[4][2], int buf, int mh) {
#pragma unroll
    for (int j = 0; j < 4; ++j)
#pragma unroll
      for (int kk = 0; kk < 2; ++kk)
        dst[j][kk] = *lds8p(As[buf][mh], wm * 64 + j * 16 + l15, kk * 32 + lk8);
  };
  auto LDBf = [&](bf16x8 (&dst)[2][2], int buf, int nh) {
#pragma unroll
    for (int jj = 0; jj < 2; ++jj)
#pragma unroll
      for (int kk = 0; kk < 2; ++kk)
        dst[jj][kk] = *lds8p(Bs[buf][nh], wn * 32 + jj * 16 + l15, kk * 32 + lk8);
  };

  f32x4 acc[8][4] = {};
  auto MMf = [&](bf16x8 (&a)[4][2], bf16x8 (&b)[2][2], int mh, int nh) {
    __builtin_amdgcn_s_setprio(1);
#pragma unroll
    for (int kk = 0; kk < 2; ++kk)
#pragma unroll
      for (int j = 0; j < 4; ++j)
#pragma unroll
        for (int jj = 0; jj < 2; ++jj)
          acc[mh * 4 + j][nh * 2 + jj] = __builtin_amdgcn_mfma_f32_16x16x32_bf16(
              a[j][kk], b[jj][kk], acc[mh * 4 + j][nh * 2 + jj], 0, 0, 0);
    __builtin_amdgcn_s_setprio(0);
  };
  auto BAR = [&]() { __builtin_amdgcn_s_barrier(); };  // bare: NO memory clobber

  STAGE_A(0, 0, 0);
  STAGE_B(0, 1, 0);
  STAGE_B(0, 0, 0);
  STAGE_A(0, 1, 0);
  STAGE_A(1, 0, 1);
  STAGE_B(1, 1, 1);
  asm volatile("s_waitcnt vmcnt(4)" ::: "memory");
  BAR();
  // prologue fragments: A0, B0 of tile 0 (buf 0)
  LDAf(aA, 0, 0);
  LDBf(bA, 0, 0);

#pragma unroll
  for (int T = 0; T < NT; ++T) {
    int cur = T & 1;  // folds under full unroll
    if (T + 1 < NT) STAGE_B(T + 1, 0, cur ^ 1);
    BAR();
    LDBf(bB, cur, 1);
    MMf(aA, bA, 0, 0);
    BAR();
    if (T + 1 < NT) STAGE_A(T + 1, 1, cur ^ 1);
    BAR();
    LDAf(aB, cur, 1);
    MMf(aA, bB, 0, 1);
    BAR();
    if (T + 2 < NT) STAGE_A(T + 2, 0, cur);
    BAR();
    MMf(aB, bB, 1, 1);
    BAR();
    if (T + 2 < NT) STAGE_B(T + 2, 1, cur);
    BAR();
    MMf(aB, bA, 1, 0);
    if (T + 1 < NT) {
      if (T == NT - 2) {
        asm volatile("s_waitcnt vmcnt(0)" ::: "memory");
      } else {
        asm volatile("s_waitcnt vmcnt(4)" ::: "memory");
      }
    }
    BAR();
    if (T + 1 < NT) {
      LDAf(aA, cur ^ 1, 0);
      LDBf(bA, cur ^ 1, 0);
    }
  }

  uint16_t* Pz = nullptr;
  if constexpr (EPI == 3) {
    int z = blockIdx.z;
    Pz = (z == 0) ? P0 : (z == 1) ? P1 : (z == 2) ? P2 : P3;
  }
#pragma unroll
  for (int mi = 0; mi < 8; ++mi) {
#pragma unroll
    for (int ni = 0; ni < 4; ++ni) {
      int gm0 = m0 + (mi >> 2) * 128 + wm * 64 + (mi & 3) * 16 + lr4;
      int gn = n0 + (ni >> 1) * 128 + wn * 32 + (ni & 1) * 16 + l15;
      if constexpr (EPI == 0) {
        int which = gn >> 10, nc = gn & 1023;
        int h = nc >> 6, dh = nc & 63;
        int bb = gm0 >> 11, s0 = gm0 & 2047;
        if (which == 2) {
          // V: write directly transposed into VTb (bh,dh,s); 4 consecutive s
          ushort4 vs;
          vs.x = f2bf(acc[mi][ni][0]);
          vs.y = f2bf(acc[mi][ni][1]);
          vs.z = f2bf(acc[mi][ni][2]);
          vs.w = f2bf(acc[mi][ni][3]);
          uint16_t* VTb = P0;  // passed via P0 slot
          *reinterpret_cast<ushort4*>(
              VTb + ((size_t)(bb * 16 + h) * 64 + dh) * S_ + s0) = vs;
        } else {
#pragma unroll
          for (int rr = 0; rr < 4; ++rr) {
            float v = acc[mi][ni][rr];
            if (which == 1) v *= SCL2K_;  // fold softmax scale into K
            ((uint16_t*)Cout)[((size_t)which * 32 + bb * 16 + h) * (S_ * 64) +
                              (size_t)(s0 + rr) * 64 + dh] = f2bf(v);
          }
        }
      } else {
#pragma unroll
        for (int rr = 0; rr < 4; ++rr) {
          int gm = gm0 + rr;
          float v = acc[mi][ni][rr];
          if constexpr (EPI == 2) {
            float u = v + bias[gn];
            float y = 0.7978845608028654f * (u + 0.044715f * u * u * u);
            float e = __expf(2.0f * y);
            float th = 1.0f - 2.0f / (e + 1.0f);  // tanh(y), inf-safe
            ((uint16_t*)Cout)[(size_t)gm * N + gn] = f2bf(0.5f * u * (1.0f + th));
          } else {
            Pz[(size_t)gm * N + gn] = f2bf(v);
          }
        }
      }
    }
  }
}

// --------- 128x128 2-phase GEMM (Wo only): out X1 bf16 = x + acc + bo ---------
template <int EPI>
__global__ __launch_bounds__(256) void gemm_bt(
    const uint16_t* __restrict__ A, const uint16_t* __restrict__ BT,
    void* __restrict__ Cout, const float* __restrict__ bias,
    const float* __restrict__ resid, int M, int N, int K) {
  __shared__ uint16_t Asm_[128 * 64];
  __shared__ uint16_t Bsm_[128 * 64];
  int t = threadIdx.x;
  int lane = t & 63, wid = t >> 6;
  int wr = wid >> 1, wc = wid & 1;
  int nwg = gridDim.x * gridDim.y;
  int bid = blockIdx.y * gridDim.x + blockIdx.x;
  int swz = (bid & 7) * (nwg >> 3) + (bid >> 3);
  int bx = swz % gridDim.x, by = swz / gridDim.x;
  int m0 = by * 128, n0 = bx * 128;
  int l15 = lane & 15, lk8 = (lane >> 4) * 8;
  f32x4 acc[4][4] = {};

  auto STAGE = [&](int k0) {
#pragma unroll
    for (int it = 0; it < 4; ++it) {
      int idx = it * 256 + t;
      int r = idx >> 3, slot = idx & 7;
      int c = (slot ^ (r & 7)) * 8;
      gload_lds16(A + (size_t)(m0 + r) * K + k0 + c, &Asm_[idx * 8]);
      gload_lds16(BT + (size_t)(n0 + r) * K + k0 + c, &Bsm_[idx * 8]);
    }
  };

  int niter = K >> 6;
  for (int ki = 0; ki < niter; ++ki) {
    __syncthreads();
    STAGE(ki * 64);
    __syncthreads();
#pragma unroll
    for (int kk = 0; kk < 2; ++kk) {
      bf16x8 a[4], b[4];
#pragma unroll
      for (int mi = 0; mi < 4; ++mi)
        a[mi] = *lds8p(Asm_, wr * 64 + mi * 16 + l15, kk * 32 + lk8);
#pragma unroll
      for (int ni = 0; ni < 4; ++ni)
        b[ni] = *lds8p(Bsm_, wc * 64 + ni * 16 + l15, kk * 32 + lk8);
#pragma unroll
      for (int mi = 0; mi < 4; ++mi)
#pragma unroll
        for (int ni = 0; ni < 4; ++ni)
          acc[mi][ni] = __builtin_amdgcn_mfma_f32_16x16x32_bf16(
              a[mi], b[ni], acc[mi][ni], 0, 0, 0);
    }
  }
  int lr4 = (lane >> 4) * 4;
#pragma unroll
  for (int mi = 0; mi < 4; ++mi) {
#pragma unroll
    for (int ni = 0; ni < 4; ++ni) {
#pragma unroll
      for (int r = 0; r < 4; ++r) {
        int gm = m0 + wr * 64 + mi * 16 + lr4 + r;
        int gn = n0 + wc * 64 + ni * 16 + l15;
        float v = acc[mi][ni][r];
        if constexpr (EPI == 1) {
          // X1 (bf16) = x (f32) + ctx@Wo + bo
          ((uint16_t*)Cout)[(size_t)gm * N + gn] =
              f2bf(resid[(size_t)gm * N + gn] + v + bias[gn]);
        }
      }
    }
  }
}

// ===== flash causal attention: split-S=3 + LPT ordering + LDS-staged 32x32 ====
__global__ __launch_bounds__(64) void attn32s_k(const uint16_t* __restrict__ Q,
                                                const uint16_t* __restrict__ Kv,
                                                const uint16_t* __restrict__ VT,
                                                uint16_t* __restrict__ Obuf,
                                                float* __restrict__ ML) {
  __shared__ uint16_t Ksm[2][32 * 64];
  __shared__ uint16_t Vsm[2][32 * 64];
  int bid = blockIdx.x;
  int bh = bid & 31;            // bid%8 == bh%8: head's K/V stays on one XCD L2
  int s = (bid >> 5) % 3;
  int qt = 63 - bid / 96;       // LPT: heaviest first
  int lane = threadIdx.x;
  int l31 = lane & 31, lh = lane >> 5;
  int nkt = qt + 1;
  int chunk = (nkt + 2) / 3;
  int t0 = s * chunk, t1 = min(nkt, t0 + chunk);
  int pb = (qt * 32 + bh) * 3 + s;

  f32x16 o0 = {}, o1 = {};
  float mrow = -3.0e38f, lsum = 0.0f;

  auto STAGE = [&](int k0, int bufi) {
#pragma unroll
    for (int c = 0; c < 4; ++c) {
      int idx = c * 64 + lane;
      int r = idx >> 3, sl = idx & 7;
      int slp = sl ^ (r & 7) ^ ((r & 8) >> 2);  // pre-swizzled source slot
      gload_lds16(Kv + ((size_t)bh * S_ + k0 + r) * 64 + slp * 8,
                  &Ksm[bufi][idx * 8]);
      int dh = 2 * r + (slp >> 2), ko = (slp & 3) * 8;
      gload_lds16(VT + ((size_t)bh * 64 + dh) * S_ + k0 + ko,
                  &Vsm[bufi][idx * 8]);
    }
  };

  if (t0 < t1) {
    int qbase = qt * 32;
    bf16x8 qf[4];
#pragma unroll
    for (int dk = 0; dk < 4; ++dk)
      qf[dk] = *reinterpret_cast<const bf16x8*>(
          Q + ((size_t)bh * S_ + qbase + l31) * 64 + dk * 16 + lh * 8);

    int buf = 0;
    STAGE(t0 * 32, 0);
    for (int t = t0; t < t1; ++t) {
      if (t + 1 < t1) {
        STAGE((t + 1) * 32, buf ^ 1);
        asm volatile("s_waitcnt vmcnt(8)" ::: "memory");
      } else {
        asm volatile("s_waitcnt vmcnt(0)" ::: "memory");
      }
      __builtin_amdgcn_sched_barrier(0);
      // QK^T swapped: Sf[key reg][q col], keys t*32..t*32+31
      f32x16 Sf = {};
      __builtin_amdgcn_s_setprio(1);
#pragma unroll
      for (int dk = 0; dk < 4; ++dk) {
        bf16x8 kf = *lds8p32(Ksm[buf], l31, dk * 16 + lh * 8);
        Sf = __builtin_amdgcn_mfma_f32_32x32x16_bf16(kf, qf[dk], Sf, 0, 0, 0);
      }
      __builtin_amdgcn_s_setprio(0);
      float sv[16];
      if (t == qt) {  // diagonal tile: key(reg) <= q(lane)
#pragma unroll
        for (int rr = 0; rr < 16; ++rr) {
          int koff = (rr & 3) + 8 * (rr >> 2) + 4 * lh;
          sv[rr] = (koff <= l31) ? Sf[rr] : -3.0e38f;
        }
      } else {
#pragma unroll
        for (int rr = 0; rr < 16; ++rr) sv[rr] = Sf[rr];
      }
      // per-lane max tree; wave reduce + rescale only on growth > 8 (exp2 dom)
      float mt16 = sv[0];
#pragma unroll
      for (int rr = 1; rr < 16; ++rr) mt16 = fmaxf(mt16, sv[rr]);
      if (__any(mt16 > mrow + 8.0f)) {
        float mt = mt16;
#pragma unroll
        for (int off = 32; off >= 1; off >>= 1)
          mt = fmaxf(mt, __shfl_xor(mt, off));
        mt = fmaxf(mt, mrow);
        float fac = __builtin_amdgcn_exp2f(mrow - mt);
        mrow = mt;
        lsum *= fac;
#pragma unroll
        for (int rr = 0; rr < 16; ++rr) { o0[rr] *= fac; o1[rr] *= fac; }
      }
      float pv[16];
#pragma unroll
      for (int rr = 0; rr < 16; ++rr) {
        pv[rr] = __builtin_amdgcn_exp2f(sv[rr] - mrow);
        lsum += pv[rr];
      }
      // P -> two bf16 A-frags (keys 0-15, 16-31) via cvt_pk + permlane32_swap
      uint32_t a0 = cvtpk_bf16(pv[0], pv[1]), b0 = cvtpk_bf16(pv[4], pv[5]);
      pl32swap(a0, b0);
      uint32_t a1 = cvtpk_bf16(pv[2], pv[3]), b1 = cvtpk_bf16(pv[6], pv[7]);
      pl32swap(a1, b1);
      u32x4v w0 = {a0, a1, b0, b1};
      bf16x8 pa0 = __builtin_bit_cast(bf16x8, w0);
      uint32_t a2 = cvtpk_bf16(pv[8], pv[9]), b2 = cvtpk_bf16(pv[12], pv[13]);
      pl32swap(a2, b2);
      uint32_t a3 = cvtpk_bf16(pv[10], pv[11]), b3 = cvtpk_bf16(pv[14], pv[15]);
      pl32swap(a3, b3);
      u32x4v w1 = {a2, a3, b2, b3};
      bf16x8 pa1 = __builtin_bit_cast(bf16x8, w1);
      // PV: o[q][dh] += P[q][key] * V[key][dh]
      int vrow = l31 >> 1, vcb = (l31 & 1) * 32 + lh * 8;
      __builtin_amdgcn_s_setprio(1);
      bf16x8 v00 = *lds8p32(Vsm[buf], vrow, vcb);
      o0 = __builtin_amdgcn_mfma_f32_32x32x16_bf16(pa0, v00, o0, 0, 0, 0);
      bf16x8 v01 = *lds8p32(Vsm[buf], vrow, vcb + 16);
      o0 = __builtin_amdgcn_mfma_f32_32x32x16_bf16(pa1, v01, o0, 0, 0, 0);
      bf16x8 v10 = *lds8p32(Vsm[buf], 16 + vrow, vcb);
      o1 = __builtin_amdgcn_mfma_f32_32x32x16_bf16(pa0, v10, o1, 0, 0, 0);
      bf16x8 v11 = *lds8p32(Vsm[buf], 16 + vrow, vcb + 16);
      o1 = __builtin_amdgcn_mfma_f32_32x32x16_bf16(pa1, v11, o1, 0, 0, 0);
      __builtin_amdgcn_s_setprio(0);
      buf ^= 1;
    }
    lsum += __shfl_xor(lsum, 32);  // combine lh halves -> full row sum for q=l31
  }

  // write partial: unnormalized o (bf16) + per-q (m, l) f32
  if (lane < 32) {
    ML[(size_t)pb * 64 + l31 * 2] = mrow;
    ML[(size_t)pb * 64 + l31 * 2 + 1] = lsum;
  }
#pragma unroll
  for (int rr = 0; rr < 16; ++rr) {
    int srow = (rr & 3) + 8 * (rr >> 2) + 4 * lh;
    size_t base = (size_t)pb * 2048 + srow * 64;
    Obuf[base + l31] = f2bf(o0[rr]);
    Obuf[base + 32 + l31] = f2bf(o1[rr]);
  }
}

// combine (3-way): ctx = sum_s o_s*2^(m_s-m) / sum_s l_s*2^(m_s-m)
__global__ __launch_bounds__(64) void attncomb_k(const uint16_t* __restrict__ Obuf,
                                                 const float* __restrict__ ML,
                                                 uint16_t* __restrict__ ctx) {
  int blk = blockIdx.x;  // qt*32 + bh
  int qt = blk >> 5, bh = blk & 31;
  int lane = threadIdx.x;
  int q = lane >> 1, half = lane & 1;
  size_t pb0 = (size_t)blk * 3;
  float m0 = ML[pb0 * 64 + q * 2], l0 = ML[pb0 * 64 + q * 2 + 1];
  float m1 = ML[(pb0 + 1) * 64 + q * 2], l1 = ML[(pb0 + 1) * 64 + q * 2 + 1];
  float m2 = ML[(pb0 + 2) * 64 + q * 2], l2 = ML[(pb0 + 2) * 64 + q * 2 + 1];
  float m = fmaxf(fmaxf(m0, m1), m2);
  float w0 = __builtin_amdgcn_exp2f(m0 - m);
  float w1 = __builtin_amdgcn_exp2f(m1 - m);
  float w2 = __builtin_amdgcn_exp2f(m2 - m);
  float invL = 1.0f / (l0 * w0 + l1 * w1 + l2 * w2);
  int b_ = bh >> 4, h_ = bh & 15;
  int srow = qt * 32 + q;
  size_t ib = pb0 * 2048 + q * 64 + half * 32;
  size_t ob = ((size_t)(b_ * S_ + srow)) * D_ + h_ * 64 + half * 32;
#pragma unroll
  for (int i = 0; i < 8; ++i) {
    ushort4 u0 = *reinterpret_cast<const ushort4*>(Obuf + ib + i * 4);
    ushort4 u1 = *reinterpret_cast<const ushort4*>(Obuf + 2048 + ib + i * 4);
    ushort4 u2 = *reinterpret_cast<const ushort4*>(Obuf + 4096 + ib + i * 4);
    ushort4 o;
    o.x = f2bf((bf2f(u0.x) * w0 + bf2f(u1.x) * w1 + bf2f(u2.x) * w2) * invL);
    o.y = f2bf((bf2f(u0.y) * w0 + bf2f(u1.y) * w1 + bf2f(u2.y) * w2) * invL);
    o.z = f2bf((bf2f(u0.z) * w0 + bf2f(u1.z) * w1 + bf2f(u2.z) * w2) * invL);
    o.w = f2bf((bf2f(u0.w) * w0 + bf2f(u1.w) * w1 + bf2f(u2.w) * w2) * invL);
    *reinterpret_cast<ushort4*>(ctx + ob + i * 4) = o;
  }
}

extern "C" void kernel_launch(void* const* d_in, const int* in_sizes, int n_in,
                              void* d_out, int out_size, void* d_ws, size_t ws_size,
                              hipStream_t stream) {
  const float* x    = (const float*)d_in[0];
  const float* Wq   = (const float*)d_in[1];
  const float* Wk   = (const float*)d_in[2];
  const float* Wv   = (const float*)d_in[3];
  const float* Wo   = (const float*)d_in[4];
  const float* bo   = (const float*)d_in[5];
  const float* W1   = (const float*)d_in[6];
  const float* b1   = (const float*)d_in[7];
  const float* W2   = (const float*)d_in[8];
  const float* b2   = (const float*)d_in[9];
  const float* ln1s = (const float*)d_in[10];
  const float* ln1b = (const float*)d_in[11];
  const float* ln2s = (const float*)d_in[12];
  const float* ln2b = (const float*)d_in[13];
  float* out = (float*)d_out;
  char* ws = (char*)d_ws;

  const size_t MB = 1024 * 1024;
  uint16_t* WQKVT = (uint16_t*)(ws + 0);        // 6 MB (dead after QKV gemm)
  uint16_t* WOT   = (uint16_t*)(ws + 6 * MB);   // 2 MB (live until Wo)
  uint16_t* W1T   = (uint16_t*)(ws + 8 * MB);   // 8 MB (live until FFN1)
  uint16_t* W2T   = (uint16_t*)(ws + 16 * MB);  // 8 MB (live until FFN2)
  uint16_t* H1    = (uint16_t*)(ws + 24 * MB);  // 8 MB (LN1/LN2 out)
  uint16_t* X1    = (uint16_t*)(ws + 32 * MB);  // 8 MB (attn residual, bf16)
  uint16_t* QKV   = (uint16_t*)(ws + 48 * MB);  // 24 MB (q,k at 48-64)
  uint16_t* VTb   = (uint16_t*)(ws + 72 * MB);  // 8 MB  (v transposed, direct)
  uint16_t* CTX   = (uint16_t*)(ws + 80 * MB);  // 8 MB
  uint16_t* FFH   = (uint16_t*)(ws + 48 * MB);  // 32 MB (reuses dead QKV/VT)
  // attn split-S=3 partials (live attn->combine; H1/X1 dead then):
  uint16_t* AOB   = (uint16_t*)(ws + 24 * MB);  // 24 MB (6144 pb x 4KB)
  float*    AML   = (float*)(ws + 0);           // 1.5 MB (WQKVT dead by attn)
  // FFN2 split-K bf16 partials (dead regions at FFN2 time):
  uint16_t* SP0   = (uint16_t*)(ws + 0);        // over WQKVT (dead)
  uint16_t* SP1   = (uint16_t*)(ws + 8 * MB);   // over W1T (dead after FFN1)
  uint16_t* SP2   = (uint16_t*)(ws + 24 * MB);  // over H1/AOB (dead after FFN1)
  uint16_t* SP3   = (uint16_t*)(ws + 80 * MB);  // over CTX (dead after Wo)

  dim3 b32x8(32, 8);
  // weight converts + LN1 in one launch
  prep_k<<<dim3(16384), b32x8, 0, stream>>>(Wq, Wk, Wv, Wo, W1, W2,
                                            WQKVT, WOT, W1T, W2T,
                                            x, ln1s, ln1b, H1);
  // QKV projections (fused N=3072), 256^2 8-phase; K pre-scaled; V written
  // directly transposed into VTb (VTb passed via the P0 slot) — no vtrans.
  gemm8<0><<<dim3(12, 16), 512, 0, stream>>>(H1, WQKVT, QKV, nullptr,
                                             VTb, nullptr, nullptr, nullptr,
                                             M_, 3072, 1024);
  const uint16_t* Qp = QKV;
  const uint16_t* Kp = QKV + (size_t)32 * S_ * 64;
  // flash causal attention: split-S=3 LPT, 6144 one-wave blocks + combine
  attn32s_k<<<dim3(6144), 64, 0, stream>>>(Qp, Kp, VTb, AOB, AML);
  attncomb_k<<<dim3(2048), 64, 0, stream>>>(AOB, AML, CTX);
  // Wo projection + bias + residual -> X1 (bf16), 128^2 path
  gemm_bt<1><<<dim3(8, 32), 256, 0, stream>>>(CTX, WOT, X1, bo, x, M_, 1024, 1024);
  // LN2 -> h2 (bf16, reuse H1); reads bf16 X1
  ln_k<<<M_, 256, 0, stream>>>(X1, ln2s, ln2b, H1);
  // FFN1 + GELU -> FFH (bf16), 256^2 8-phase
  gemm8<2><<<dim3(16, 16), 512, 0, stream>>>(H1, W1T, FFH, b1,
                                             nullptr, nullptr, nullptr, nullptr,
                                             M_, 4096, 1024);
  // FFN2 split-K=4 (ksz=1024), 256^2 8-phase: bf16 partials (plain stores)
  gemm8<3><<<dim3(4, 16, 4), 512, 0, stream>>>(FFH, W2T, nullptr, nullptr,
                                               SP0, SP1, SP2, SP3,
                                               M_, 1024, 4096);
  // out = X1 (bf16) + b2 + sum(partials)
  reduce4_k<<<M_, 256, 0, stream>>>(SP0, SP1, SP2, SP3, X1, b2, out);
}